// Round 8
// baseline (270.941 us; speedup 1.0000x reference)
//
#include <hip/hip_runtime.h>
#include <hip/hip_bf16.h>

#define N_NODES 50000
#define N_EDGES 1600000
#define N_GRAPHS 512
#define VOCAB 1000
#define EMB 32
#define HID 64
#define N_CLASS 2

#define NPART 8
#define PART_NODES (N_NODES / NPART)   // 6250
#define MAXDEG 96                      // Poisson(32) tail @96 ~ 4e-20/node

#define L2P_BLOCKS 768                 // 3 blocks/CU co-resident
#define L2P_WAVES (L2P_BLOCKS * 4)     // 3072
#define L2P_CHUNK ((N_NODES + L2P_WAVES - 1) / L2P_WAVES)  // 17

typedef int iv4 __attribute__((ext_vector_type(4)));   // native vector for nt-load

__device__ __forceinline__ float rdlane(float v, int k) {
    return __int_as_float(__builtin_amdgcn_readlane(__float_as_int(v), k));
}
// unpack a uint holding two bf16: lo -> float (u<<16), hi -> float (u & 0xFFFF0000)
__device__ __forceinline__ float bflo(unsigned int u) { return __uint_as_float(u << 16); }
__device__ __forceinline__ float bfhi(unsigned int u) { return __uint_as_float(u & 0xFFFF0000u); }

// ---------------- CSR build: dst-partitioned, padded, nt streams, 4-deep pipeline ----
// csr[d*MAXDEG + pos] = (cls << 16) | src ; cursor[d] = degree
__global__ __launch_bounds__(256) void fill_part_kernel(
        const int* __restrict__ src, const int* __restrict__ dst,
        const int* __restrict__ x_ids, int* __restrict__ cursor,
        int* __restrict__ csr) {
    int p = blockIdx.x & (NPART - 1);       // partition (XCD round-robin heuristic)
    int bp = blockIdx.x >> 3;
    int nblk = gridDim.x >> 3;
    int lo = p * PART_NODES, hi = lo + PART_NODES;
    const iv4* dst4 = (const iv4*)dst;
    const iv4* src4 = (const iv4*)src;
    const int n4 = N_EDGES / 4;
    int stride = nblk * blockDim.x;
    for (int t = bp * blockDim.x + threadIdx.x; t < n4; t += stride) {
        iv4 d = __builtin_nontemporal_load(dst4 + t);
        iv4 s = __builtin_nontemporal_load(src4 + t);
        bool o0 = (d.x >= lo) & (d.x < hi);
        bool o1 = (d.y >= lo) & (d.y < hi);
        bool o2 = (d.z >= lo) & (d.z < hi);
        bool o3 = (d.w >= lo) & (d.w < hi);
        int p0, p1, p2, p3;
        if (o0) p0 = atomicAdd(&cursor[d.x], 1);
        if (o1) p1 = atomicAdd(&cursor[d.y], 1);
        if (o2) p2 = atomicAdd(&cursor[d.z], 1);
        if (o3) p3 = atomicAdd(&cursor[d.w], 1);
        if (o0) csr[d.x * MAXDEG + p0] = (x_ids[s.x] << 16) | s.x;
        if (o1) csr[d.y * MAXDEG + p1] = (x_ids[s.y] << 16) | s.y;
        if (o2) csr[d.z * MAXDEG + p2] = (x_ids[s.z] << 16) | s.z;
        if (o3) csr[d.w * MAXDEG + p3] = (x_ids[s.w] << 16) | s.w;
    }
}

// ---------------- precompute folded layer-1 tables ----------------
// e1b = bf16(embed @ w1l)  (VOCAB x HID), e1r = embed @ w1r (fp32)
__global__ void precompute_e1_kernel(const float* __restrict__ embed,
                                     const float* __restrict__ w1l,
                                     const float* __restrict__ w1r,
                                     __hip_bfloat16* __restrict__ e1b,
                                     float* __restrict__ e1r) {
    int id = blockIdx.x * blockDim.x + threadIdx.x;
    if (id >= VOCAB * HID) return;
    int v = id >> 6, j = id & 63;
    float a = 0.0f, b = 0.0f;
    #pragma unroll
    for (int k = 0; k < EMB; ++k) {
        float ev = embed[v * EMB + k];
        a = fmaf(ev, w1l[k * HID + j], a);
        b = fmaf(ev, w1r[k * HID + j], b);
    }
    e1b[id] = __float2bfloat16(a);
    e1r[id] = b;
}

// Half-wave gather core: lanes 0-31 take even edges, 32-63 odd edges; each lane
// loads ushort2 (feats 2*fl, 2*fl+1) of its edge's table row. 4 chains (8 edges/iter).
// Returns per-lane (lo,hi) sums combined across halves, then permuted so lane j
// holds feature j's sum.
template <typename IdxFn>
__device__ __forceinline__ float gather_half_wave(
        const unsigned int* __restrict__ tab,  // rows of 32 uints (64 bf16)
        const int* __restrict__ csr, int s, int e, int lane, IdxFn idxof) {
    int half = lane >> 5;
    int fl = lane & 31;
    float a0l = 0.f, a0h = 0.f, a1l = 0.f, a1h = 0.f;
    float a2l = 0.f, a2h = 0.f, a3l = 0.f, a3h = 0.f;
    int k = s;
    for (; k + 8 <= e; k += 8) {
        int4 qa = *reinterpret_cast<const int4*>(csr + k);      // edges k..k+3
        int4 qb = *reinterpret_cast<const int4*>(csr + k + 4);  // edges k+4..k+7
        int n0 = idxof(half ? qa.y : qa.x);
        int n1 = idxof(half ? qa.w : qa.z);
        int n2 = idxof(half ? qb.y : qb.x);
        int n3 = idxof(half ? qb.w : qb.z);
        unsigned int u0 = tab[n0 * 32 + fl];
        unsigned int u1 = tab[n1 * 32 + fl];
        unsigned int u2 = tab[n2 * 32 + fl];
        unsigned int u3 = tab[n3 * 32 + fl];
        a0l += bflo(u0); a0h += bfhi(u0);
        a1l += bflo(u1); a1h += bfhi(u1);
        a2l += bflo(u2); a2h += bfhi(u2);
        a3l += bflo(u3); a3h += bfhi(u3);
    }
    for (; k < e; k += 2) {
        int idx = k + half;
        if (idx < e) {
            unsigned int u = tab[idxof(csr[idx]) * 32 + fl];
            a0l += bflo(u); a0h += bfhi(u);
        }
    }
    float lo = (a0l + a1l) + (a2l + a3l);
    float hi = (a0h + a1h) + (a2h + a3h);
    lo += __shfl_xor(lo, 32);
    hi += __shfl_xor(hi, 32);
    // lane j wants feature j = component (j&1) of lane (j>>1)
    float va = __shfl(lo, lane >> 1);
    float vb = __shfl(hi, lane >> 1);
    return (lane & 1) ? vb : va;
}

// ---------------- layer 1: agg (bf16 class-table gather) + linear + relu ----------------
__global__ __launch_bounds__(256) void agg1_lin1_kernel(
        const int* __restrict__ x_ids, const int* __restrict__ csr,
        const int* __restrict__ deg_arr, const __hip_bfloat16* __restrict__ e1b,
        const float* __restrict__ e1r, const float* __restrict__ b1,
        float* __restrict__ h1, __hip_bfloat16* __restrict__ h1b) {
    int id = blockIdx.x * blockDim.x + threadIdx.x;
    int i = __builtin_amdgcn_readfirstlane(id >> 6);
    int lane = threadIdx.x & 63;
    int s = i * MAXDEG;
    int deg = deg_arr[i];
    float sum = gather_half_wave((const unsigned int*)e1b, csr, s, s + deg, lane,
                                 [](int v) { return (int)(((unsigned int)v) >> 16); });
    float mean = sum / fmaxf((float)deg, 1.0f);
    float h = fmaxf(mean + b1[lane] + e1r[x_ids[i] * HID + lane], 0.0f);
    int o = i * HID + lane;
    h1[o] = h;
    h1b[o] = __float2bfloat16(h);
}

// ---------------- layer 2 aggregation only: mean2 = mean of h1b rows ----------------
__global__ __launch_bounds__(256) void agg2_mean_kernel(
        const __hip_bfloat16* __restrict__ h1b, const int* __restrict__ csr,
        const int* __restrict__ deg_arr, float* __restrict__ mean2) {
    int id = blockIdx.x * blockDim.x + threadIdx.x;
    int i = __builtin_amdgcn_readfirstlane(id >> 6);
    int lane = threadIdx.x & 63;
    int s = i * MAXDEG;
    int deg = deg_arr[i];
    float sum = gather_half_wave((const unsigned int*)h1b, csr, s, s + deg, lane,
                                 [](int v) { return v & 0xFFFF; });
    mean2[i * HID + lane] = sum / fmaxf((float)deg, 1.0f);
}

// ---------------- layer 2 linear + relu + pool: weights in VGPRs ----------------
__global__ __launch_bounds__(256) void lin2_pool_kernel(
        const float* __restrict__ mean2, const float* __restrict__ h1,
        const float* __restrict__ w2l, const float* __restrict__ b2,
        const float* __restrict__ w2r, const int* __restrict__ batch,
        float* __restrict__ gsum) {
    int lane = threadIdx.x & 63;
    int wv = (blockIdx.x * blockDim.x + threadIdx.x) >> 6;   // global wave id
    int i0 = wv * L2P_CHUNK;
    int i1 = i0 + L2P_CHUNK; if (i1 > N_NODES) i1 = N_NODES;
    if (i0 >= N_NODES) return;
    float wl[HID], wr[HID];
    #pragma unroll
    for (int k = 0; k < HID; ++k) {
        wl[k] = w2l[k * HID + lane];
        wr[k] = w2r[k * HID + lane];
    }
    float bj = b2[lane];
    int curg = __builtin_amdgcn_readfirstlane(batch[i0]);
    float accp = 0.0f;
    float m = mean2[i0 * HID + lane];
    float h = h1[i0 * HID + lane];
    for (int i = i0; i < i1; ++i) {
        float mn = 0.f, hn = 0.f;
        if (i + 1 < i1) {                      // prefetch next rows
            mn = mean2[(i + 1) * HID + lane];
            hn = h1[(i + 1) * HID + lane];
        }
        int g = __builtin_amdgcn_readfirstlane(batch[i]);
        if (g != curg) {
            atomicAdd(&gsum[curg * HID + lane], accp);
            accp = 0.0f;
            curg = g;
        }
        float z = bj;
        #pragma unroll
        for (int k = 0; k < HID; ++k)
            z = fmaf(rdlane(m, k), wl[k], fmaf(rdlane(h, k), wr[k], z));
        accp += fmaxf(z, 0.0f);
        m = mn; h = hn;
    }
    atomicAdd(&gsum[curg * HID + lane], accp);
}

// ---------------- output: pool-normalize + final linear ----------------
__global__ void out_kernel(const float* __restrict__ gsum, const int* __restrict__ batch,
                           const float* __restrict__ w_out, const float* __restrict__ b_out,
                           float* __restrict__ out) {
    int id = blockIdx.x * blockDim.x + threadIdx.x;
    if (id >= N_GRAPHS * N_CLASS) return;
    int g = id >> 1, c = id & 1;
    int lo = 0, hi = N_NODES;
    while (lo < hi) { int mid = (lo + hi) >> 1; if (batch[mid] < g) lo = mid + 1; else hi = mid; }
    int first = lo;
    lo = 0; hi = N_NODES;
    while (lo < hi) { int mid = (lo + hi) >> 1; if (batch[mid] <= g) lo = mid + 1; else hi = mid; }
    float cnt = (float)(lo - first);
    float inv = 1.0f / fmaxf(cnt, 1.0f);
    float acc = b_out[c];
    #pragma unroll
    for (int j = 0; j < HID; ++j)
        acc = fmaf(gsum[g * HID + j] * inv, w_out[j * N_CLASS + c], acc);
    out[id] = acc;
}

// ---------------- launch ----------------

extern "C" void kernel_launch(void* const* d_in, const int* in_sizes, int n_in,
                              void* d_out, int out_size, void* d_ws, size_t ws_size,
                              hipStream_t stream) {
    const int*   x_ids = (const int*)d_in[0];
    const int*   edge  = (const int*)d_in[1];
    const int*   batch = (const int*)d_in[2];
    const float* embed = (const float*)d_in[3];
    const float* w1l   = (const float*)d_in[4];
    const float* b1    = (const float*)d_in[5];
    const float* w1r   = (const float*)d_in[6];
    const float* w2l   = (const float*)d_in[7];
    const float* b2    = (const float*)d_in[8];
    const float* w2r   = (const float*)d_in[9];
    const float* wout  = (const float*)d_in[10];
    const float* bout  = (const float*)d_in[11];
    const int* src = edge;
    const int* dst = edge + N_EDGES;
    float* out = (float*)d_out;

    char* ws = (char*)d_ws;
    size_t off = 0;
    auto alloc = [&](size_t bytes) -> void* {
        void* p = ws + off;
        off += (bytes + 255) & ~(size_t)255;
        return p;
    };
    float*           h1     = (float*)alloc((size_t)N_NODES * HID * 4);          // 12.8 MB
    __hip_bfloat16*  h1b    = (__hip_bfloat16*)alloc((size_t)N_NODES * HID * 2); // 6.4 MB
    float*           mean2  = (float*)alloc((size_t)N_NODES * HID * 4);          // 12.8 MB
    int*             csr    = (int*)alloc((size_t)N_NODES * MAXDEG * 4);         // 19.2 MB
    int*             cursor = (int*)alloc((size_t)N_NODES * 4);                  // 200 KB
    __hip_bfloat16*  e1b    = (__hip_bfloat16*)alloc((size_t)VOCAB * HID * 2);   // 128 KB
    float*           e1r    = (float*)alloc((size_t)VOCAB * HID * 4);            // 256 KB
    float*           gsum   = (float*)alloc((size_t)N_GRAPHS * HID * 4);         // 128 KB

    hipMemsetAsync(cursor, 0, (size_t)N_NODES * 4, stream);
    hipMemsetAsync(gsum, 0, (size_t)N_GRAPHS * HID * 4, stream);

    const int B = 256;
    precompute_e1_kernel<<<(VOCAB * HID + B - 1) / B, B, 0, stream>>>(embed, w1l, w1r, e1b, e1r);
    fill_part_kernel<<<NPART * 128, B, 0, stream>>>(src, dst, x_ids, cursor, csr);

    agg1_lin1_kernel<<<N_NODES * HID / B, B, 0, stream>>>(x_ids, csr, cursor,
                                                          e1b, e1r, b1, h1, h1b);
    agg2_mean_kernel<<<N_NODES * HID / B, B, 0, stream>>>(h1b, csr, cursor, mean2);
    lin2_pool_kernel<<<L2P_BLOCKS, B, 0, stream>>>(mean2, h1, w2l, b2, w2r, batch, gsum);
    out_kernel<<<(N_GRAPHS * N_CLASS + B - 1) / B, B, 0, stream>>>(gsum, batch, wout, bout, out);
}

// Round 9
// 265.809 us; speedup vs baseline: 1.0193x; 1.0193x over previous
//
#include <hip/hip_runtime.h>
#include <hip/hip_bf16.h>

#define N_NODES 50000
#define N_EDGES 1600000
#define N_GRAPHS 512
#define VOCAB 1000
#define EMB 32
#define HID 64
#define N_CLASS 2

#define NPART 8
#define PART_NODES (N_NODES / NPART)   // 6250
#define MAXDEG 96                      // Poisson(32) tail @96 ~ 4e-20/node

#define FILL_BLOCKS (NPART * 200)      // 1600 blocks -> 6400 waves, ~1 int4 pack/thread

#define L2P_BLOCKS 768                 // 3 blocks/CU co-resident
#define L2P_WAVES (L2P_BLOCKS * 4)     // 3072
#define L2P_CHUNK ((N_NODES + L2P_WAVES - 1) / L2P_WAVES)  // 17

typedef int iv4 __attribute__((ext_vector_type(4)));

__device__ __forceinline__ float rdlane(float v, int k) {
    return __int_as_float(__builtin_amdgcn_readlane(__float_as_int(v), k));
}
// unpack a uint holding two bf16: lo -> float (u<<16), hi -> float (u & 0xFFFF0000)
__device__ __forceinline__ float bflo(unsigned int u) { return __uint_as_float(u << 16); }
__device__ __forceinline__ float bfhi(unsigned int u) { return __uint_as_float(u & 0xFFFF0000u); }

// ---------------- CSR build: dst-partitioned, padded, max concurrent atomic chains ----
// csr[d*MAXDEG + pos] = (cls << 16) | src ; cursor[d] = degree
__global__ __launch_bounds__(256) void fill_part_kernel(
        const int* __restrict__ src, const int* __restrict__ dst,
        const int* __restrict__ x_ids, int* __restrict__ cursor,
        int* __restrict__ csr) {
    int p = blockIdx.x & (NPART - 1);       // partition (XCD round-robin heuristic)
    int bp = blockIdx.x >> 3;
    int nblk = gridDim.x >> 3;
    int lo = p * PART_NODES, hi = lo + PART_NODES;
    const iv4* dst4 = (const iv4*)dst;
    const iv4* src4 = (const iv4*)src;
    const int n4 = N_EDGES / 4;
    int stride = nblk * blockDim.x;
    for (int t = bp * blockDim.x + threadIdx.x; t < n4; t += stride) {
        iv4 d = dst4[t];
        iv4 s = src4[t];
        bool o0 = (d.x >= lo) & (d.x < hi);
        bool o1 = (d.y >= lo) & (d.y < hi);
        bool o2 = (d.z >= lo) & (d.z < hi);
        bool o3 = (d.w >= lo) & (d.w < hi);
        int p0, p1, p2, p3;
        if (o0) p0 = atomicAdd(&cursor[d.x], 1);
        if (o1) p1 = atomicAdd(&cursor[d.y], 1);
        if (o2) p2 = atomicAdd(&cursor[d.z], 1);
        if (o3) p3 = atomicAdd(&cursor[d.w], 1);
        if (o0) csr[d.x * MAXDEG + p0] = (x_ids[s.x] << 16) | s.x;
        if (o1) csr[d.y * MAXDEG + p1] = (x_ids[s.y] << 16) | s.y;
        if (o2) csr[d.z * MAXDEG + p2] = (x_ids[s.z] << 16) | s.z;
        if (o3) csr[d.w * MAXDEG + p3] = (x_ids[s.w] << 16) | s.w;
    }
}

// ---------------- precompute folded layer-1 tables ----------------
// e1b = bf16(embed @ w1l)  (VOCAB x HID), e1r = embed @ w1r (fp32)
__global__ void precompute_e1_kernel(const float* __restrict__ embed,
                                     const float* __restrict__ w1l,
                                     const float* __restrict__ w1r,
                                     __hip_bfloat16* __restrict__ e1b,
                                     float* __restrict__ e1r) {
    int id = blockIdx.x * blockDim.x + threadIdx.x;
    if (id >= VOCAB * HID) return;
    int v = id >> 6, j = id & 63;
    float a = 0.0f, b = 0.0f;
    #pragma unroll
    for (int k = 0; k < EMB; ++k) {
        float ev = embed[v * EMB + k];
        a = fmaf(ev, w1l[k * HID + j], a);
        b = fmaf(ev, w1r[k * HID + j], b);
    }
    e1b[id] = __float2bfloat16(a);
    e1r[id] = b;
}

// Half-wave gather core: lanes 0-31 take even edges, 32-63 odd edges; each lane
// loads ushort2 (feats 2*fl, 2*fl+1) of its edge's table row. 4 chains (8 edges/iter).
template <typename IdxFn>
__device__ __forceinline__ float gather_half_wave(
        const unsigned int* __restrict__ tab,  // rows of 32 uints (64 bf16)
        const int* __restrict__ csr, int s, int e, int lane, IdxFn idxof) {
    int half = lane >> 5;
    int fl = lane & 31;
    float a0l = 0.f, a0h = 0.f, a1l = 0.f, a1h = 0.f;
    float a2l = 0.f, a2h = 0.f, a3l = 0.f, a3h = 0.f;
    int k = s;
    for (; k + 8 <= e; k += 8) {
        int4 qa = *reinterpret_cast<const int4*>(csr + k);      // edges k..k+3
        int4 qb = *reinterpret_cast<const int4*>(csr + k + 4);  // edges k+4..k+7
        int n0 = idxof(half ? qa.y : qa.x);
        int n1 = idxof(half ? qa.w : qa.z);
        int n2 = idxof(half ? qb.y : qb.x);
        int n3 = idxof(half ? qb.w : qb.z);
        unsigned int u0 = tab[n0 * 32 + fl];
        unsigned int u1 = tab[n1 * 32 + fl];
        unsigned int u2 = tab[n2 * 32 + fl];
        unsigned int u3 = tab[n3 * 32 + fl];
        a0l += bflo(u0); a0h += bfhi(u0);
        a1l += bflo(u1); a1h += bfhi(u1);
        a2l += bflo(u2); a2h += bfhi(u2);
        a3l += bflo(u3); a3h += bfhi(u3);
    }
    for (; k < e; k += 2) {
        int idx = k + half;
        if (idx < e) {
            unsigned int u = tab[idxof(csr[idx]) * 32 + fl];
            a0l += bflo(u); a0h += bfhi(u);
        }
    }
    float lo = (a0l + a1l) + (a2l + a3l);
    float hi = (a0h + a1h) + (a2h + a3h);
    lo += __shfl_xor(lo, 32);
    hi += __shfl_xor(hi, 32);
    // lane j wants feature j = component (j&1) of lane (j>>1)
    float va = __shfl(lo, lane >> 1);
    float vb = __shfl(hi, lane >> 1);
    return (lane & 1) ? vb : va;
}

// ---------------- layer 1: agg (bf16 class-table gather) + linear + relu ----------------
__global__ __launch_bounds__(256) void agg1_lin1_kernel(
        const int* __restrict__ x_ids, const int* __restrict__ csr,
        const int* __restrict__ deg_arr, const __hip_bfloat16* __restrict__ e1b,
        const float* __restrict__ e1r, const float* __restrict__ b1,
        float* __restrict__ h1, __hip_bfloat16* __restrict__ h1b) {
    int id = blockIdx.x * blockDim.x + threadIdx.x;
    int i = __builtin_amdgcn_readfirstlane(id >> 6);
    int lane = threadIdx.x & 63;
    int s = i * MAXDEG;
    int deg = deg_arr[i];
    float sum = gather_half_wave((const unsigned int*)e1b, csr, s, s + deg, lane,
                                 [](int v) { return (int)(((unsigned int)v) >> 16); });
    float mean = sum / fmaxf((float)deg, 1.0f);
    float h = fmaxf(mean + b1[lane] + e1r[x_ids[i] * HID + lane], 0.0f);
    int o = i * HID + lane;
    h1[o] = h;
    h1b[o] = __float2bfloat16(h);
}

// ---------------- layer 2 aggregation only: mean2 = mean of h1b rows ----------------
__global__ __launch_bounds__(256) void agg2_mean_kernel(
        const __hip_bfloat16* __restrict__ h1b, const int* __restrict__ csr,
        const int* __restrict__ deg_arr, float* __restrict__ mean2) {
    int id = blockIdx.x * blockDim.x + threadIdx.x;
    int i = __builtin_amdgcn_readfirstlane(id >> 6);
    int lane = threadIdx.x & 63;
    int s = i * MAXDEG;
    int deg = deg_arr[i];
    float sum = gather_half_wave((const unsigned int*)h1b, csr, s, s + deg, lane,
                                 [](int v) { return v & 0xFFFF; });
    mean2[i * HID + lane] = sum / fmaxf((float)deg, 1.0f);
}

// ---------------- layer 2 linear + relu + pool: weights in VGPRs ----------------
__global__ __launch_bounds__(256) void lin2_pool_kernel(
        const float* __restrict__ mean2, const float* __restrict__ h1,
        const float* __restrict__ w2l, const float* __restrict__ b2,
        const float* __restrict__ w2r, const int* __restrict__ batch,
        float* __restrict__ gsum) {
    int lane = threadIdx.x & 63;
    int wv = (blockIdx.x * blockDim.x + threadIdx.x) >> 6;   // global wave id
    int i0 = wv * L2P_CHUNK;
    int i1 = i0 + L2P_CHUNK; if (i1 > N_NODES) i1 = N_NODES;
    if (i0 >= N_NODES) return;
    float wl[HID], wr[HID];
    #pragma unroll
    for (int k = 0; k < HID; ++k) {
        wl[k] = w2l[k * HID + lane];
        wr[k] = w2r[k * HID + lane];
    }
    float bj = b2[lane];
    int curg = __builtin_amdgcn_readfirstlane(batch[i0]);
    float accp = 0.0f;
    float m = mean2[i0 * HID + lane];
    float h = h1[i0 * HID + lane];
    for (int i = i0; i < i1; ++i) {
        float mn = 0.f, hn = 0.f;
        if (i + 1 < i1) {                      // prefetch next rows
            mn = mean2[(i + 1) * HID + lane];
            hn = h1[(i + 1) * HID + lane];
        }
        int g = __builtin_amdgcn_readfirstlane(batch[i]);
        if (g != curg) {
            atomicAdd(&gsum[curg * HID + lane], accp);
            accp = 0.0f;
            curg = g;
        }
        float z = bj;
        #pragma unroll
        for (int k = 0; k < HID; ++k)
            z = fmaf(rdlane(m, k), wl[k], fmaf(rdlane(h, k), wr[k], z));
        accp += fmaxf(z, 0.0f);
        m = mn; h = hn;
    }
    atomicAdd(&gsum[curg * HID + lane], accp);
}

// ---------------- output: pool-normalize + final linear ----------------
__global__ void out_kernel(const float* __restrict__ gsum, const int* __restrict__ batch,
                           const float* __restrict__ w_out, const float* __restrict__ b_out,
                           float* __restrict__ out) {
    int id = blockIdx.x * blockDim.x + threadIdx.x;
    if (id >= N_GRAPHS * N_CLASS) return;
    int g = id >> 1, c = id & 1;
    int lo = 0, hi = N_NODES;
    while (lo < hi) { int mid = (lo + hi) >> 1; if (batch[mid] < g) lo = mid + 1; else hi = mid; }
    int first = lo;
    lo = 0; hi = N_NODES;
    while (lo < hi) { int mid = (lo + hi) >> 1; if (batch[mid] <= g) lo = mid + 1; else hi = mid; }
    float cnt = (float)(lo - first);
    float inv = 1.0f / fmaxf(cnt, 1.0f);
    float acc = b_out[c];
    #pragma unroll
    for (int j = 0; j < HID; ++j)
        acc = fmaf(gsum[g * HID + j] * inv, w_out[j * N_CLASS + c], acc);
    out[id] = acc;
}

// ---------------- launch ----------------

extern "C" void kernel_launch(void* const* d_in, const int* in_sizes, int n_in,
                              void* d_out, int out_size, void* d_ws, size_t ws_size,
                              hipStream_t stream) {
    const int*   x_ids = (const int*)d_in[0];
    const int*   edge  = (const int*)d_in[1];
    const int*   batch = (const int*)d_in[2];
    const float* embed = (const float*)d_in[3];
    const float* w1l   = (const float*)d_in[4];
    const float* b1    = (const float*)d_in[5];
    const float* w1r   = (const float*)d_in[6];
    const float* w2l   = (const float*)d_in[7];
    const float* b2    = (const float*)d_in[8];
    const float* w2r   = (const float*)d_in[9];
    const float* wout  = (const float*)d_in[10];
    const float* bout  = (const float*)d_in[11];
    const int* src = edge;
    const int* dst = edge + N_EDGES;
    float* out = (float*)d_out;

    char* ws = (char*)d_ws;
    size_t off = 0;
    auto alloc = [&](size_t bytes) -> void* {
        void* p = ws + off;
        off += (bytes + 255) & ~(size_t)255;
        return p;
    };
    float*           h1     = (float*)alloc((size_t)N_NODES * HID * 4);          // 12.8 MB
    __hip_bfloat16*  h1b    = (__hip_bfloat16*)alloc((size_t)N_NODES * HID * 2); // 6.4 MB
    float*           mean2  = (float*)alloc((size_t)N_NODES * HID * 4);          // 12.8 MB
    int*             csr    = (int*)alloc((size_t)N_NODES * MAXDEG * 4);         // 19.2 MB
    int*             cursor = (int*)alloc((size_t)N_NODES * 4);                  // 200 KB
    __hip_bfloat16*  e1b    = (__hip_bfloat16*)alloc((size_t)VOCAB * HID * 2);   // 128 KB
    float*           e1r    = (float*)alloc((size_t)VOCAB * HID * 4);            // 256 KB
    float*           gsum   = (float*)alloc((size_t)N_GRAPHS * HID * 4);         // 128 KB

    hipMemsetAsync(cursor, 0, (size_t)N_NODES * 4, stream);
    hipMemsetAsync(gsum, 0, (size_t)N_GRAPHS * HID * 4, stream);

    const int B = 256;
    precompute_e1_kernel<<<(VOCAB * HID + B - 1) / B, B, 0, stream>>>(embed, w1l, w1r, e1b, e1r);
    fill_part_kernel<<<FILL_BLOCKS, B, 0, stream>>>(src, dst, x_ids, cursor, csr);

    agg1_lin1_kernel<<<N_NODES * HID / B, B, 0, stream>>>(x_ids, csr, cursor,
                                                          e1b, e1r, b1, h1, h1b);
    agg2_mean_kernel<<<N_NODES * HID / B, B, 0, stream>>>(h1b, csr, cursor, mean2);
    lin2_pool_kernel<<<L2P_BLOCKS, B, 0, stream>>>(mean2, h1, w2l, b2, w2r, batch, gsum);
    out_kernel<<<(N_GRAPHS * N_CLASS + B - 1) / B, B, 0, stream>>>(gsum, batch, wout, bout, out);
}